// Round 5
// baseline (371.004 us; speedup 1.0000x reference)
//
#include <hip/hip_runtime.h>
#include <hip/hip_bf16.h>

// int8 quantized conv2d 3x3 s1 p1. B=32 Cin=128 H=W=56 Cout=256.
// Implicit GEMM, LDS-pipelined MFMA i32_16x16x64_i8.
// A = weights packed [chunk][cout][64B], B = padded NHWC int8 activations.

#define B_    32
#define CIN   128
#define H_    56
#define W_    56
#define COUT  256
#define HP    58
#define WP    58
#define HWP   (H_*W_)        // 3136
#define NPIX  (B_*HWP)       // 100352
#define NCHUNK 18            // K=1152 / 64
#define CHUNK_BYTES (COUT*64) // 16384

#define QX_BLOCKS (NPIX/64)   // 1568
#define QW_BLOCKS 288         // 73728/256

typedef int int4v __attribute__((ext_vector_type(4)));

__device__ __forceinline__ void gld_lds16(const void* g, void* l) {
    __builtin_amdgcn_global_load_lds(
        (const __attribute__((address_space(1))) unsigned int*)g,
        (__attribute__((address_space(3))) unsigned int*)l, 16, 0, 0);
}

__device__ __forceinline__ int q8(float v, float s) {
    return (int)fminf(127.f, fmaxf(-127.f, rintf(v * s)));
}

// ---------------- pad/scale zero (933KB border ring, replaces 14MB memset) ----------------
__global__ __launch_bounds__(256) void pad_zero_kernel(signed char* __restrict__ xq,
                                                       unsigned* __restrict__ scales) {
    const int b = blockIdx.x;
    if (b == 0 && threadIdx.x < 2) scales[threadIdx.x] = 0;
    int4* base = (int4*)(xq + (long)b * HP * WP * CIN);
    const int ROWI4 = WP * CIN / 16;   // 464
    int4 z; z.x = 0; z.y = 0; z.z = 0; z.w = 0;
    for (int i = threadIdx.x; i < ROWI4; i += 256) base[i] = z;                  // row 0
    int4* top = base + 57 * ROWI4;
    for (int i = threadIdx.x; i < ROWI4; i += 256) top[i] = z;                   // row 57
    for (int idx = threadIdx.x; idx < 56 * 16; idx += 256) {                     // cols 0 & 57
        const int h = idx >> 4, c = idx & 15;
        const int w = (c < 8) ? 0 : 57, p = c & 7;
        base[(h + 1) * ROWI4 + w * (CIN / 16) + p] = z;
    }
}

// ---------------- fused amax over x and w ----------------
__global__ __launch_bounds__(256) void amax_kernel(const float4* __restrict__ x, long n4x,
                                                   const float4* __restrict__ wt, long n4w,
                                                   unsigned* __restrict__ scales) {
    const float4* p; long n4; unsigned* slot; long start, stride;
    if (blockIdx.x < 2048) {
        p = x; n4 = n4x; slot = scales;
        start = (long)blockIdx.x * 256 + threadIdx.x; stride = 2048L * 256;
    } else {
        p = wt; n4 = n4w; slot = scales + 1;
        start = (long)(blockIdx.x - 2048) * 256 + threadIdx.x; stride = 128L * 256;
    }
    float m = 0.f;
    for (long i = start; i < n4; i += stride) {
        float4 v = p[i];
        m = fmaxf(m, fmaxf(fmaxf(fabsf(v.x), fabsf(v.y)), fmaxf(fabsf(v.z), fabsf(v.w))));
    }
    __shared__ float red[256];
    red[threadIdx.x] = m; __syncthreads();
    for (int s = 128; s > 0; s >>= 1) {
        if (threadIdx.x < s) red[threadIdx.x] = fmaxf(red[threadIdx.x], red[threadIdx.x + s]);
        __syncthreads();
    }
    if (threadIdx.x == 0) atomicMax(slot, __float_as_uint(red[0]));  // all >=0
}

// ---------------- fused quantize: x -> padded NHWC int8, w -> packed chunks ----------------
// Blocks [0, QX_BLOCKS): 64 pixels x 128 channels, float4 loads + LDS transpose.
// Blocks [QX_BLOCKS, QX_BLOCKS+QW_BLOCKS): weight pack.
__global__ __launch_bounds__(256) void quant_kernel(const float* __restrict__ x,
        const float* __restrict__ wt, const unsigned* __restrict__ scales,
        signed char* __restrict__ xq, signed char* __restrict__ wq) {
    const int t = threadIdx.x;
    if (blockIdx.x < QX_BLOCKS) {
        // ---- activation tile: b = blk/49, pixels [tile*64, tile*64+64) ----
        const int blk = blockIdx.x;
        const int b = blk / 49, tile = blk % 49;
        const int hw0 = tile * 64;
        const float sx = 127.0f / __uint_as_float(scales[0]);
        __shared__ int ldsq[64 * 33];
        const float* base = x + (long)b * CIN * HWP + hw0;
        const int pos = t & 15;           // float4 index within 64-px run
        const int cq = t >> 4;            // 0..15
#pragma unroll
        for (int pi = 0; pi < 2; ++pi) {
            const int c4 = pi * 16 + cq;  // 0..31
            float4 f[4];
#pragma unroll
            for (int u = 0; u < 4; ++u)
                f[u] = *(const float4*)(base + (long)(c4 * 4 + u) * HWP + pos * 4);
#pragma unroll
            for (int p = 0; p < 4; ++p) {
                const float e0 = (p == 0) ? f[0].x : (p == 1) ? f[0].y : (p == 2) ? f[0].z : f[0].w;
                const float e1 = (p == 0) ? f[1].x : (p == 1) ? f[1].y : (p == 2) ? f[1].z : f[1].w;
                const float e2 = (p == 0) ? f[2].x : (p == 1) ? f[2].y : (p == 2) ? f[2].z : f[2].w;
                const float e3 = (p == 0) ? f[3].x : (p == 1) ? f[3].y : (p == 2) ? f[3].z : f[3].w;
                const int pk = (q8(e0, sx) & 0xff) | ((q8(e1, sx) & 0xff) << 8)
                             | ((q8(e2, sx) & 0xff) << 16) | ((q8(e3, sx) & 0xff) << 24);
                ldsq[(pos * 4 + p) * 33 + c4] = pk;
            }
        }
        __syncthreads();
        // coalesced int4 NHWC stores: 512 int4 / block
#pragma unroll
        for (int s = 0; s < 2; ++s) {
            const int idx = s * 256 + t;
            const int px = idx >> 3, c16 = idx & 7;
            const int hw = hw0 + px;
            const int h = hw / W_, w = hw % W_;
            int4 v;
            v.x = ldsq[px * 33 + c16 * 4 + 0];
            v.y = ldsq[px * 33 + c16 * 4 + 1];
            v.z = ldsq[px * 33 + c16 * 4 + 2];
            v.w = ldsq[px * 33 + c16 * 4 + 3];
            *(int4*)(xq + (((long)b * HP + h + 1) * WP + (w + 1)) * CIN + c16 * 16) = v;
        }
    } else {
        // ---- weight pack: OIHW f32 -> [chunk][cout][64] int8 ----
        const int id = (blockIdx.x - QX_BLOCKS) * 256 + t;   // 73728 total
        const float sw = 127.0f / __uint_as_float(scales[1]);
        const int co = id / 288;
        const int r  = id % 288;
        const int tp = r / 32;    // tap
        const int c4 = r % 32;    // ci/4
        int pk = 0;
#pragma unroll
        for (int u = 0; u < 4; ++u) {
            float v = wt[(co * CIN + c4 * 4 + u) * 9 + tp];
            pk |= (q8(v, sw) & 0xff) << (u * 8);
        }
        const int k = tp * CIN + c4 * 4;
        *(int*)(wq + (long)(k >> 6) * CHUNK_BYTES + co * 64 + (k & 63)) = pk;
    }
}

// ---------------- conv: LDS-pipelined MFMA implicit GEMM ----------------
// block 512 thr = 8 waves; tile 256 co x 128 px; wave tile 64x64.
// LDS K-major: As[buf][g][co][16B] (16KB), Bs[buf][g][px][16B] (8KB). 48KB -> 3 blocks/CU.
__global__ __launch_bounds__(512, 6) void conv_kernel(
        const signed char* __restrict__ xq, const signed char* __restrict__ wq,
        const float* __restrict__ bias, const unsigned* __restrict__ scales,
        float* __restrict__ out) {
    __shared__ signed char As[2][16384];
    __shared__ signed char Bs[2][8192];

    const int tid = threadIdx.x;
    const int lane = tid & 63;
    const int wv = tid >> 6;        // 0..7
    const int ln = lane & 15;
    const int g  = lane >> 4;

    const int wco = wv >> 1;        // co quarter 0..3
    const int wpx = wv & 1;         // px half 0..1
    const int px_blk = blockIdx.x * 128;

    // A staging: wave does insts e=wv*2, wv*2+1; e -> (gA=e>>2, qA=e&3)
    const int e0 = wv * 2, e1 = e0 + 1;
    const int gA0 = e0 >> 2, qA0 = e0 & 3;
    const int gA1 = e1 >> 2, qA1 = e1 & 3;
    const signed char* srcA0 = wq + (qA0 * 64 + lane) * 64 + gA0 * 16;
    const signed char* srcA1 = wq + (qA1 * 64 + lane) * 64 + gA1 * 16;
    const int ldsA0 = gA0 * 4096 + qA0 * 1024 + lane * 16;
    const int ldsA1 = gA1 * 4096 + qA1 * 1024 + lane * 16;

    // B staging: wave does inst wv -> (gB=wv>>1, halfB=wv&1); per-lane fixed px row
    const int gB = wv >> 1, halfB = wv & 1;
    const int pxs = px_blk + halfB * 64 + lane;
    const int bS = pxs / HWP, hwS = pxs % HWP;
    const int hS = hwS / W_, wS = hwS % W_;
    const signed char* srcB = xq + ((bS * HP + hS) * WP + wS) * CIN + gB * 16;
    const int ldsB = gB * 2048 + halfB * 1024 + lane * 16;

#define STAGE(c, buf) { \
    const int tap_ = (c) >> 1; \
    const int toff_ = ((tap_ / 3) * WP + (tap_ % 3)) * CIN + ((c) & 1) * 64; \
    gld_lds16(srcA0 + (c) * CHUNK_BYTES, &As[buf][ldsA0]); \
    gld_lds16(srcA1 + (c) * CHUNK_BYTES, &As[buf][ldsA1]); \
    gld_lds16(srcB + toff_, &Bs[buf][ldsB]); }

    int4v acc[4][4] = {};
    STAGE(0, 0);
#pragma unroll
    for (int c = 0; c < NCHUNK; ++c) {
        const int cur = c & 1;
        __syncthreads();                       // chunk c staged (vmcnt drained at barrier)
        if (c + 1 < NCHUNK) STAGE(c + 1, cur ^ 1);
        int4v Af[4], Bf[4];
#pragma unroll
        for (int i = 0; i < 4; ++i)
            Af[i] = *(const int4v*)&As[cur][g * 4096 + (wco * 64 + i * 16 + ln) * 16];
#pragma unroll
        for (int j = 0; j < 4; ++j)
            Bf[j] = *(const int4v*)&Bs[cur][g * 2048 + (wpx * 64 + j * 16 + ln) * 16];
#pragma unroll
        for (int i = 0; i < 4; ++i)
#pragma unroll
            for (int j = 0; j < 4; ++j)
                acc[i][j] = __builtin_amdgcn_mfma_i32_16x16x64_i8(Af[i], Bf[j], acc[i][j], 0, 0, 0);
    }
#undef STAGE

    const float ax = __uint_as_float(scales[0]);
    const float aw = __uint_as_float(scales[1]);
    const float inv = 1.0f / ((127.0f / ax) * (127.0f / aw));

    // D 16x16: col(=px) = lane&15, row(=co) = g*4 + r
#pragma unroll
    for (int i = 0; i < 4; ++i) {
        const int co = wco * 64 + i * 16 + g * 4;
#pragma unroll
        for (int r = 0; r < 4; ++r) {
            const float bsv = bias[co + r];
#pragma unroll
            for (int j = 0; j < 4; ++j) {
                const int px = px_blk + wpx * 64 + j * 16 + ln;
                const int b = px / HWP, hw = px % HWP;
                out[((long)(b * COUT + co + r)) * HWP + hw] = (float)acc[i][j][r] * inv + bsv;
            }
        }
    }
}

extern "C" void kernel_launch(void* const* d_in, const int* in_sizes, int n_in,
                              void* d_out, int out_size, void* d_ws, size_t ws_size,
                              hipStream_t stream) {
    const float* x  = (const float*)d_in[0];
    const float* wt = (const float*)d_in[1];
    const float* bs = (const float*)d_in[2];
    float* out = (float*)d_out;

    unsigned* scales = (unsigned*)d_ws;                  // [0]=amax_x, [1]=amax_w (bits)
    const size_t XQ_OFF   = 256;
    const size_t XQ_BYTES = (size_t)B_ * HP * WP * CIN;  // 13,778,944
    signed char* xq = (signed char*)d_ws + XQ_OFF;
    signed char* wq = xq + XQ_BYTES;

    pad_zero_kernel<<<B_, 256, 0, stream>>>(xq, scales);

    const long n4x = (long)B_ * CIN * H_ * W_ / 4;
    const long n4w = (long)COUT * CIN * 9 / 4;
    amax_kernel<<<2176, 256, 0, stream>>>((const float4*)x, n4x, (const float4*)wt, n4w, scales);

    quant_kernel<<<QX_BLOCKS + QW_BLOCKS, 256, 0, stream>>>(x, wt, scales, xq, wq);

    conv_kernel<<<NPIX / 128, 512, 0, stream>>>(xq, wq, bs, scales, out);
}